// Round 6
// baseline (70.461 us; speedup 1.0000x reference)
//
#include <hip/hip_runtime.h>
#include <math.h>

#define N_BINS 256
#define TAU 0.01f
#define EPS 1e-10f
#define HW (512*512)
#define Q 4081            // quant levels; Q-1 = 4080 = 16*255 so t_q - b_j = (q-16j)/4080
#define QSTRIDE 4096
#define MWIN 208          // |q-16j| <= 208 -> dropped weight exp(-13) ~ 2e-6 (negligible)
#define WTAB (2*MWIN+1)   // 417
#define WPADN 432         // 16*27, zero-padded tail
#define NP 27             // taps per phase: m = 16*(p-13)+r
#define CFP_STRIDE 289    // odd stride -> 2-way bank aliasing only (free)
#define NPART 64          // blocks per batch
#define BMAX 4
#define HSTRIDE 16        // one 64B line per bin -> per-line atomic chains run in parallel

// Two-gen parity: g_genA bumped ONLY by K2 (read only by K1); g_genB bumped ONLY by K1
// (read only by K2). Every bump->read crosses a kernel boundary => no intra-kernel
// ordering needed, uniform parity per kernel. K1 iter n: par = genA&1 = n&1; K2 reads
// par = (genB-1)&1 = n&1 (genB already bumped by its K1). K1's s==0 block zeroes the
// par^1 buffer (touched by nobody else this iteration). hist zero-init at load covers
// iteration 0. Graph-replay and whole-run rocprof-replay safe (state self-consistent).
__device__ __align__(64) unsigned int g_genA = 0u;
__device__ __align__(64) unsigned int g_genB = 0u;
__device__ __align__(16) float g_hist[2][BMAX][N_BINS * HSTRIDE];   // 512 KB, zero-init

// -------- K1: fine hist (float LDS atomics, no scatter pass) -> register conv ->
// 16-lane shuffle reduce-scatter -> one global atomicAdd per bin --------
__global__ __launch_bounds__(512) void hist_conv_kernel(const float* __restrict__ x) {
    __shared__ float cfp[16 * CFP_STRIDE];   // 18.5 KB
    __shared__ float wtE[WPADN];
    __shared__ unsigned int sgen;
    const int b   = blockIdx.y;
    const int s   = blockIdx.x;
    const int tid = threadIdx.x;
    const int r   = tid & 15;
    const int t   = tid >> 4;        // 0..31

    // pixel loads issued first; LDS init overlaps their latency
    const float4* xb = (const float4*)(x + (size_t)b * HW + (size_t)s * 4096);
    const float4 p0 = xb[tid];
    const float4 p1 = xb[512 + tid];

    if (tid == 0)
        sgen = __hip_atomic_load(&g_genA, __ATOMIC_RELAXED, __HIP_MEMORY_SCOPE_AGENT);
    for (int i = tid; i < 16 * CFP_STRIDE; i += 512) cfp[i] = 0.f;
    for (int i = tid; i < WPADN; i += 512) {
        const float d = (float)(i - MWIN) * (1.0f / 4080.f);
        wtE[i] = (i < WTAB) ? __expf(-d * d * (1.0f / (2.0f * TAU * TAU))) : 0.f;
    }
    __syncthreads();
    const int par = (int)(sgen & 1u);

    // zero NEXT iteration's buffer (one block per batch; write-through so next
    // kernel's LLC atomics can't see a stale line)
    if (s == 0 && tid < N_BINS)
        __hip_atomic_store(&g_hist[par ^ 1][b][tid * HSTRIDE], 0.f,
                           __ATOMIC_RELAXED, __HIP_MEMORY_SCOPE_AGENT);

    // ---- fine histogram straight into conv layout (counts exact in fp32) ----
    {
        const float4 vv[2] = {p0, p1};
#pragma unroll
        for (int i = 0; i < 2; ++i) {
            const float4 v = vv[i];
            int q0 = __float2int_rn(v.x * 4080.f);
            int q1 = __float2int_rn(v.y * 4080.f);
            int q2 = __float2int_rn(v.z * 4080.f);
            int q3 = __float2int_rn(v.w * 4080.f);
            q0 = min(max(q0, 0), Q - 1); q1 = min(max(q1, 0), Q - 1);
            q2 = min(max(q2, 0), Q - 1); q3 = min(max(q3, 0), Q - 1);
            atomicAdd(&cfp[(q0 & 15) * CFP_STRIDE + (q0 >> 4) + 13], 1.f);
            atomicAdd(&cfp[(q1 & 15) * CFP_STRIDE + (q1 >> 4) + 13], 1.f);
            atomicAdd(&cfp[(q2 & 15) * CFP_STRIDE + (q2 >> 4) + 13], 1.f);
            atomicAdd(&cfp[(q3 & 15) * CFP_STRIDE + (q3 >> 4) + 13], 1.f);
        }
    }
    __syncthreads();

    // ---- register-blocked conv; thread (r,t) computes bins 8t..8t+7 for phase r ----
    float v0, v1, v2, v3, v4, v5, v6, v7;
    {
        float creg[34];
        const float* cbase = &cfp[r * CFP_STRIDE + 8 * t];
#pragma unroll
        for (int k = 0; k < 34; ++k) creg[k] = cbase[k];
        float acc[8];
#pragma unroll
        for (int uu = 0; uu < 8; ++uu) acc[uu] = 0.f;
#pragma unroll
        for (int p = 0; p < NP; ++p) {
            const float w = wtE[16 * p + r];
#pragma unroll
            for (int uu = 0; uu < 8; ++uu) acc[uu] += w * creg[uu + p];
        }
        v0 = acc[0]; v1 = acc[1]; v2 = acc[2]; v3 = acc[3];
        v4 = acc[4]; v5 = acc[5]; v6 = acc[6]; v7 = acc[7];
    }

    // ---- 16-lane reduce-scatter over phases r (xor 1,2,4,8); lane r ends with
    // bin 8t+(r&7) summed over all 16 phases. Keep slot j iff j-bit == r-bit. ----
    {
        const bool h1 = (r & 1) != 0;
        float s0 = h1 ? v0 : v1, s1 = h1 ? v2 : v3, s2 = h1 ? v4 : v5, s3 = h1 ? v6 : v7;
        const float q0 = __shfl_xor(s0, 1, 64), q1 = __shfl_xor(s1, 1, 64);
        const float q2 = __shfl_xor(s2, 1, 64), q3 = __shfl_xor(s3, 1, 64);
        const float w0 = (h1 ? v1 : v0) + q0;   // slot 0|(r&1)
        const float w1 = (h1 ? v3 : v2) + q1;   // slot 2|(r&1)
        const float w2 = (h1 ? v5 : v4) + q2;   // slot 4|(r&1)
        const float w3 = (h1 ? v7 : v6) + q3;   // slot 6|(r&1)

        const bool h2 = (r & 2) != 0;
        float u0 = h2 ? w0 : w1, u1 = h2 ? w2 : w3;
        const float e0 = __shfl_xor(u0, 2, 64), e1 = __shfl_xor(u1, 2, 64);
        const float x0 = (h2 ? w1 : w0) + e0;   // slot (r&3)
        const float x1 = (h2 ? w3 : w2) + e1;   // slot 4|(r&3)

        const bool h4 = (r & 4) != 0;
        float u2 = h4 ? x0 : x1;
        const float e2 = __shfl_xor(u2, 4, 64);
        const float y = (h4 ? x1 : x0) + e2;    // slot r&7

        const float z = y + __shfl_xor(y, 8, 64);   // summed over all 16 phases

        if (r < 8)
            atomicAdd(&g_hist[par][b][(8 * t + r) * HSTRIDE], z);
    }

    if (b == 0 && s == 0 && tid == 0)
        __hip_atomic_fetch_add(&g_genB, 1u, __ATOMIC_RELAXED, __HIP_MEMORY_SCOPE_AGENT);
}

// -------- K2: 1KB hist readback -> scan -> LUT (interior sw closed-form) -> equalize ---
__global__ __launch_bounds__(512) void lut_equalize_kernel(const float* __restrict__ x,
                                                           float* __restrict__ out) {
    __shared__ float Tl[QSTRIDE];        // 16 KB
    __shared__ float wtE[WPADN];
    __shared__ float cdfnp[288];
    __shared__ float onesp[288];
    __shared__ float wsum[4];
    __shared__ float h0s;
    __shared__ unsigned int sgen;
    const int b    = blockIdx.y;
    const int s    = blockIdx.x;
    const int tid  = threadIdx.x;
    const int r    = tid & 15;
    const int t    = tid >> 4;       // 0..31
    const int lane = tid & 63;

    // pixel loads issued first (independent of everything until equalize)
    const float4* xb = (const float4*)(x + (size_t)b * HW + (size_t)s * 4096);
    float4 px[2];
    px[0] = xb[tid];
    px[1] = xb[512 + tid];

    if (tid == 0)
        sgen = __hip_atomic_load(&g_genB, __ATOMIC_RELAXED, __HIP_MEMORY_SCOPE_AGENT);
    for (int i = tid; i < 288; i += 512) {
        cdfnp[i] = 0.f;
        onesp[i] = (i >= 13 && i < 269) ? 1.f : 0.f;
    }
    for (int i = tid; i < WPADN; i += 512) {
        const float d = (float)(i - MWIN) * (1.0f / 4080.f);
        wtE[i] = (i < WTAB) ? __expf(-d * d * (1.0f / (2.0f * TAU * TAU))) : 0.f;
    }
    __syncthreads();
    const int par = (int)((sgen - 1u) & 1u);

    // ---- 1KB coherent readback + wave-shuffle scan + cdf normalization ----
    float val = 0.f, hv = 0.f;
    if (tid < N_BINS) {
        hv = __hip_atomic_load(&g_hist[par][b][tid * HSTRIDE], __ATOMIC_RELAXED,
                               __HIP_MEMORY_SCOPE_AGENT);
        val = hv;
#pragma unroll
        for (int d = 1; d < 64; d <<= 1) {
            const float n = __shfl_up(val, (unsigned)d, 64);
            if (lane >= d) val += n;
        }
        if (lane == 63) wsum[tid >> 6] = val;
        if (tid == 0) h0s = hv;
    }
    __syncthreads();
    if (tid < N_BINS) {
        float prefix = 0.f, total = 0.f;
#pragma unroll
        for (int w2 = 0; w2 < 4; ++w2) {
            const float ws = wsum[w2];
            if (w2 < (tid >> 6)) prefix += ws;
            total += ws;
        }
        val += prefix;
        const float inv  = 1.0f / (total + EPS);
        const float cdf0 = h0s * inv;
        cdfnp[tid + 13] = (val * inv - cdf0) / (1.0f - cdf0 + EPS);
    }
    __syncthreads();

    // ---- output LUT. Interior threads (t in [2,29]): every onesp tap == 1, so
    // sw[uu] == sum_p wtE[16p+r] -- skip the second conv entirely. ----
    {
        float creg[34];
        const int base = 8 * t;
#pragma unroll
        for (int k = 0; k < 34; ++k) creg[k] = cdfnp[base + k];
        float acc[8];
#pragma unroll
        for (int uu = 0; uu < 8; ++uu) acc[uu] = 0.f;

        if (t >= 2 && t <= 29) {
            float swt = 0.f;
#pragma unroll
            for (int p = 0; p < NP; ++p) {
                const float w = wtE[16 * p + r];
                swt += w;
#pragma unroll
                for (int uu = 0; uu < 8; ++uu) acc[uu] += w * creg[uu - p + 26];
            }
            const float dinv = 1.0f / (swt + EPS);
#pragma unroll
            for (int uu = 0; uu < 8; ++uu)
                Tl[16 * (8 * t + uu) + r] = acc[uu] * dinv;
        } else {
            float oreg[34], sw[8];
#pragma unroll
            for (int k = 0; k < 34; ++k) oreg[k] = onesp[base + k];
#pragma unroll
            for (int uu = 0; uu < 8; ++uu) sw[uu] = 0.f;
#pragma unroll
            for (int p = 0; p < NP; ++p) {
                const float w = wtE[16 * p + r];
#pragma unroll
                for (int uu = 0; uu < 8; ++uu) {
                    const int k = uu - p + 26;   // in [0,34)
                    acc[uu] += w * creg[k];
                    sw[uu]  += w * oreg[k];
                }
            }
#pragma unroll
            for (int uu = 0; uu < 8; ++uu)
                Tl[16 * (8 * t + uu) + r] = acc[uu] / (sw[uu] + EPS);
        }
    }
    __syncthreads();

    // ---- equalize register-held pixels via LUT lerp ----
    float4* ob = (float4*)(out + (size_t)b * HW + (size_t)s * 4096);
#pragma unroll
    for (int i = 0; i < 2; ++i) {
        const float4 v = px[i];
        const float vv[4] = {v.x, v.y, v.z, v.w};
        float res[4];
#pragma unroll
        for (int k2 = 0; k2 < 4; ++k2) {
            const float u = vv[k2] * 4080.f;
            int q = (int)u;
            q = min(max(q, 0), Q - 2);
            const float frac = u - (float)q;
            const float t0 = Tl[q], t1 = Tl[q + 1];
            res[k2] = fmaf(frac, t1 - t0, t0);
        }
        ob[i * 512 + tid] = make_float4(res[0], res[1], res[2], res[3]);
    }

    if (b == 0 && s == 0 && tid == 0)
        __hip_atomic_fetch_add(&g_genA, 1u, __ATOMIC_RELAXED, __HIP_MEMORY_SCOPE_AGENT);
}

extern "C" void kernel_launch(void* const* d_in, const int* in_sizes, int n_in,
                              void* d_out, int out_size, void* d_ws, size_t ws_size,
                              hipStream_t stream) {
    const float* x = (const float*)d_in[0];
    float* out     = (float*)d_out;
    const int B    = in_sizes[0] / HW;   // = 4

    hist_conv_kernel<<<dim3(NPART, B), 512, 0, stream>>>(x);
    lut_equalize_kernel<<<dim3(NPART, B), 512, 0, stream>>>(x, out);
}

// Round 7
// 66.997 us; speedup vs baseline: 1.0517x; 1.0517x over previous
//
#include <hip/hip_runtime.h>
#include <math.h>

#define N_BINS 256
#define TAU 0.01f
#define EPS 1e-10f
#define HW (512*512)
#define Q 4081            // quant levels; Q-1 = 4080 = 16*255 so t_q - b_j = (q-16j)/4080
#define MWIN 208          // |q-16j| <= 208 -> dropped weight exp(-13) ~ 2e-6 (negligible)
#define WTAB (2*MWIN+1)   // 417
#define WPADN 432         // 16*27, zero-padded tail
#define NP 27             // taps per phase: m = 16*(p-13)+r
#define CFP_STRIDE 289    // odd stride -> 2-way bank aliasing only (free)
#define NPART 64          // blocks per batch
#define REDS 260          // red row stride (floats); 260*4 bytes is 16B-aligned

// -------- K1: fine hist (float LDS atomics, straight into conv layout) ->
// register-blocked conv -> 16-lane shuffle reduce-scatter -> plain partT store --------
// vs baseline K1: no int hist, no scatter pass, no ph transpose stage; 2 barriers total.
__global__ __launch_bounds__(512) void hist_conv_kernel(const float* __restrict__ x,
                                                        float* __restrict__ partT) {
    __shared__ float cfp[16 * CFP_STRIDE];   // 18.5 KB
    __shared__ float wtE[WPADN];
    const int b   = blockIdx.y;
    const int s   = blockIdx.x;
    const int tid = threadIdx.x;
    const int r   = tid & 15;
    const int t   = tid >> 4;        // 0..31

    // pixel loads issued first; LDS init overlaps their latency
    const float4* xb = (const float4*)(x + (size_t)b * HW + (size_t)s * 4096);
    const float4 p0 = xb[tid];
    const float4 p1 = xb[512 + tid];

    for (int i = tid; i < 16 * CFP_STRIDE; i += 512) cfp[i] = 0.f;
    for (int i = tid; i < WPADN; i += 512) {
        const float d = (float)(i - MWIN) * (1.0f / 4080.f);
        wtE[i] = (i < WTAB) ? __expf(-d * d * (1.0f / (2.0f * TAU * TAU))) : 0.f;
    }
    __syncthreads();

    // ---- fine histogram straight into phase-transposed conv layout (exact in fp32) ----
    {
        const float4 vv[2] = {p0, p1};
#pragma unroll
        for (int i = 0; i < 2; ++i) {
            const float4 v = vv[i];
            int q0 = __float2int_rn(v.x * 4080.f);
            int q1 = __float2int_rn(v.y * 4080.f);
            int q2 = __float2int_rn(v.z * 4080.f);
            int q3 = __float2int_rn(v.w * 4080.f);
            q0 = min(max(q0, 0), Q - 1); q1 = min(max(q1, 0), Q - 1);
            q2 = min(max(q2, 0), Q - 1); q3 = min(max(q3, 0), Q - 1);
            atomicAdd(&cfp[(q0 & 15) * CFP_STRIDE + (q0 >> 4) + 13], 1.f);
            atomicAdd(&cfp[(q1 & 15) * CFP_STRIDE + (q1 >> 4) + 13], 1.f);
            atomicAdd(&cfp[(q2 & 15) * CFP_STRIDE + (q2 >> 4) + 13], 1.f);
            atomicAdd(&cfp[(q3 & 15) * CFP_STRIDE + (q3 >> 4) + 13], 1.f);
        }
    }
    __syncthreads();

    // ---- register-blocked conv; thread (r,t) computes bins 8t..8t+7 for phase r ----
    float v0, v1, v2, v3, v4, v5, v6, v7;
    {
        float creg[34];
        const float* cbase = &cfp[r * CFP_STRIDE + 8 * t];
#pragma unroll
        for (int k = 0; k < 34; ++k) creg[k] = cbase[k];
        float acc[8];
#pragma unroll
        for (int uu = 0; uu < 8; ++uu) acc[uu] = 0.f;
#pragma unroll
        for (int p = 0; p < NP; ++p) {
            const float w = wtE[16 * p + r];
#pragma unroll
            for (int uu = 0; uu < 8; ++uu) acc[uu] += w * creg[uu + p];
        }
        v0 = acc[0]; v1 = acc[1]; v2 = acc[2]; v3 = acc[3];
        v4 = acc[4]; v5 = acc[5]; v6 = acc[6]; v7 = acc[7];
    }

    // ---- 16-lane reduce-scatter over phases (xor 1,2,4,8); lane r ends with
    // bin 8t+(r&7) summed over all 16 phases; lanes r<8 store (validated r6). ----
    {
        const bool h1 = (r & 1) != 0;
        float s0 = h1 ? v0 : v1, s1 = h1 ? v2 : v3, s2 = h1 ? v4 : v5, s3 = h1 ? v6 : v7;
        const float q0 = __shfl_xor(s0, 1, 64), q1 = __shfl_xor(s1, 1, 64);
        const float q2 = __shfl_xor(s2, 1, 64), q3 = __shfl_xor(s3, 1, 64);
        const float w0 = (h1 ? v1 : v0) + q0;
        const float w1 = (h1 ? v3 : v2) + q1;
        const float w2 = (h1 ? v5 : v4) + q2;
        const float w3 = (h1 ? v7 : v6) + q3;

        const bool h2 = (r & 2) != 0;
        float u0 = h2 ? w0 : w1, u1 = h2 ? w2 : w3;
        const float e0 = __shfl_xor(u0, 2, 64), e1 = __shfl_xor(u1, 2, 64);
        const float x0 = (h2 ? w1 : w0) + e0;
        const float x1 = (h2 ? w3 : w2) + e1;

        const bool h4 = (r & 4) != 0;
        float u2 = h4 ? x0 : x1;
        const float e2 = __shfl_xor(u2, 4, 64);
        const float y = (h4 ? x1 : x0) + e2;

        const float z = y + __shfl_xor(y, 8, 64);

        if (r < 8)
            partT[((size_t)b * NPART + s) * N_BINS + 8 * t + r] = z;
    }
}

// -------- K2: cacheable partT reduce (L2-served after first touch) -> scan ->
// LUT (interior closed-form denominator, validated r6) -> equalize --------
__global__ __launch_bounds__(512) void lut_equalize_kernel(const float* __restrict__ x,
                                                           const float* __restrict__ partT,
                                                           float* __restrict__ out) {
    __shared__ float Tl[16 * N_BINS];    // 16 KB
    __shared__ float wtE[WPADN];
    __shared__ float cdfnp[288];
    __shared__ float onesp[288];
    __shared__ __align__(16) float red[8 * REDS];    // 8.3 KB
    __shared__ float wsum[4];
    __shared__ float h0s;
    const int b    = blockIdx.y;
    const int s    = blockIdx.x;
    const int tid  = threadIdx.x;
    const int r    = tid & 15;
    const int t    = tid >> 4;       // 0..31
    const int wv   = tid >> 6;       // wave 0..7
    const int lane = tid & 63;

    for (int i = tid; i < 288; i += 512) {
        cdfnp[i] = 0.f;
        onesp[i] = (i >= 13 && i < 269) ? 1.f : 0.f;
    }
    for (int i = tid; i < WPADN; i += 512) {
        const float d = (float)(i - MWIN) * (1.0f / 4080.f);
        wtE[i] = (i < WTAB) ? __expf(-d * d * (1.0f / (2.0f * TAU * TAU))) : 0.f;
    }

    // pixel loads issued early (independent of the reduction)
    const float4* xb = (const float4*)(x + (size_t)b * HW + (size_t)s * 4096);
    float4 px[2];
#pragma unroll
    for (int i = 0; i < 2; ++i) px[i] = xb[i * 512 + tid];

    // reduce 64x256 partial matrix: wave wv sums rows 8wv..8wv+7 (lane-contiguous float4)
    {
        const float4* base4 = (const float4*)(partT + (size_t)b * NPART * N_BINS);
        float4 a4 = make_float4(0.f, 0.f, 0.f, 0.f);
#pragma unroll
        for (int rr = 0; rr < 8; ++rr) {
            const float4 v = base4[(size_t)(8 * wv + rr) * 64 + lane];
            a4.x += v.x; a4.y += v.y; a4.z += v.z; a4.w += v.w;
        }
        ((float4*)&red[wv * REDS])[lane] = a4;
    }
    __syncthreads();

    // cross-wave reduce + wave-shuffle scan over 256 bins + cdf normalization
    float val = 0.f, hv = 0.f;
    if (tid < N_BINS) {
#pragma unroll
        for (int w2 = 0; w2 < 8; ++w2) hv += red[w2 * REDS + tid];
        val = hv;
#pragma unroll
        for (int d = 1; d < 64; d <<= 1) {
            const float n = __shfl_up(val, (unsigned)d, 64);
            if (lane >= d) val += n;
        }
        if (lane == 63) wsum[tid >> 6] = val;
        if (tid == 0) h0s = hv;
    }
    __syncthreads();
    if (tid < N_BINS) {
        float prefix = 0.f, total = 0.f;
#pragma unroll
        for (int w2 = 0; w2 < 4; ++w2) {
            const float ws = wsum[w2];
            if (w2 < (tid >> 6)) prefix += ws;
            total += ws;
        }
        val += prefix;
        const float inv  = 1.0f / (total + EPS);
        const float cdf0 = h0s * inv;
        cdfnp[tid + 13] = (val * inv - cdf0) / (1.0f - cdf0 + EPS);
    }
    __syncthreads();

    // ---- output LUT. Interior threads (t in [2,29]): every onesp tap == 1, so
    // sw[uu] == sum_p wtE[16p+r] -- skip the second conv entirely. ----
    {
        float creg[34];
        const int base = 8 * t;
#pragma unroll
        for (int k = 0; k < 34; ++k) creg[k] = cdfnp[base + k];
        float acc[8];
#pragma unroll
        for (int uu = 0; uu < 8; ++uu) acc[uu] = 0.f;

        if (t >= 2 && t <= 29) {
            float swt = 0.f;
#pragma unroll
            for (int p = 0; p < NP; ++p) {
                const float w = wtE[16 * p + r];
                swt += w;
#pragma unroll
                for (int uu = 0; uu < 8; ++uu) acc[uu] += w * creg[uu - p + 26];
            }
            const float dinv = 1.0f / (swt + EPS);
#pragma unroll
            for (int uu = 0; uu < 8; ++uu)
                Tl[16 * (8 * t + uu) + r] = acc[uu] * dinv;
        } else {
            float oreg[34], sw[8];
#pragma unroll
            for (int k = 0; k < 34; ++k) oreg[k] = onesp[base + k];
#pragma unroll
            for (int uu = 0; uu < 8; ++uu) sw[uu] = 0.f;
#pragma unroll
            for (int p = 0; p < NP; ++p) {
                const float w = wtE[16 * p + r];
#pragma unroll
                for (int uu = 0; uu < 8; ++uu) {
                    const int k = uu - p + 26;   // in [0,34)
                    acc[uu] += w * creg[k];
                    sw[uu]  += w * oreg[k];
                }
            }
#pragma unroll
            for (int uu = 0; uu < 8; ++uu)
                Tl[16 * (8 * t + uu) + r] = acc[uu] / (sw[uu] + EPS);
        }
    }
    __syncthreads();

    // ---- equalize register-held pixels via LUT lerp ----
    float4* ob = (float4*)(out + (size_t)b * HW + (size_t)s * 4096);
#pragma unroll
    for (int i = 0; i < 2; ++i) {
        const float4 v = px[i];
        const float vv[4] = {v.x, v.y, v.z, v.w};
        float res[4];
#pragma unroll
        for (int k2 = 0; k2 < 4; ++k2) {
            const float u = vv[k2] * 4080.f;
            int q = (int)u;
            q = min(max(q, 0), Q - 2);
            const float frac = u - (float)q;
            const float t0 = Tl[q], t1 = Tl[q + 1];
            res[k2] = fmaf(frac, t1 - t0, t0);
        }
        ob[i * 512 + tid] = make_float4(res[0], res[1], res[2], res[3]);
    }
}

extern "C" void kernel_launch(void* const* d_in, const int* in_sizes, int n_in,
                              void* d_out, int out_size, void* d_ws, size_t ws_size,
                              hipStream_t stream) {
    const float* x = (const float*)d_in[0];
    float* out     = (float*)d_out;
    const int B    = in_sizes[0] / HW;   // = 4

    float* partT = (float*)d_ws;         // B*64*256 floats = 256 KB, plain stores (no memset)

    hist_conv_kernel<<<dim3(NPART, B), 512, 0, stream>>>(x, partT);
    lut_equalize_kernel<<<dim3(NPART, B), 512, 0, stream>>>(x, partT, out);
}